// Round 1
// baseline (91.442 us; speedup 1.0000x reference)
//
#include <hip/hip_runtime.h>
#include <hip/hip_bf16.h>
#include <math.h>

// Problem constants
#define LSEQ   512
#define DDIM   1024
#define KDIM   256       // K
#define COLS   256       // LATENT
#define ROWS   4096      // B * NTOK * NSEC
#define COEF   0.1f

// Tiling: block 32 rows x 64 cols, EIGHT waves (wave = one 16x16 MFMA tile),
// full K=256 in ONE phase, ONE barrier. Grid 128x4 = 512 blocks @ 512 thr
// = 2 blocks/CU -> 16 waves/CU (was 8 with 256 thr).
//
// R10 theory: harness poison fills (2 x 41us, 256MiB each) are a fixed
// ~82us floor; the spectral kernel residual is ~9us vs a ~3us BW floor ->
// latency-bound staging (only 2 waves/SIMD were hiding ~900cy HBM latency).
// Fix: double resident waves at IDENTICAL global traffic + LDS (48KB),
// and cluster all 12 global float4 loads per thread before any cvt/LDS
// write so they issue back-to-back (max outstanding vmcnt).
//
// Semantics collapse (verified R1-R8): spectral chain ==
//   out[row,o] = tanh( scale(row)*dot(enc_row, W[o,:]) + b[o] )
// Inline fp32->bf16 via v_cvt_pk_bf16_f32 (__float22bfloat162_rn).
// 1-pass bf16 verified safe: R8 absmax 0.0103 < 2e-2.
// LDS: 16B slot = one 8-bf16 MFMA frag; stored[r][p] = logical[r][p ^ (r&15)]
// -> conflict-free b128 reads and writes, zero padding, 48 KB, one barrier.
// Known-bad: fp32 LDS-LDS (~19.6us); global/scalar W inner loop (45-47us);
// 1 wave/SIMD (R6); inline Dekker split (R7); 2-kernel bf16 (R8).

#define TR     32
#define TC     64

typedef __attribute__((ext_vector_type(8))) short short8;    // 8 bf16 frag
typedef __attribute__((ext_vector_type(4))) float float4v;   // MFMA C/D

__device__ __forceinline__ float tanh_fast(float x) {
    // 1 - 2/(e^{2x}+1): exact +/-inf limits, ~1e-6 abs err via v_exp_f32
    return 1.0f - 2.0f / (__expf(2.0f * x) + 1.0f);
}

__device__ __forceinline__ uint4 pack8_bf16(const float4 x0, const float4 x1) {
    union { __hip_bfloat162 h2[4]; uint4 u4; } pk;
    pk.h2[0] = __float22bfloat162_rn(make_float2(x0.x, x0.y));  // k0 low, k1 high
    pk.h2[1] = __float22bfloat162_rn(make_float2(x0.z, x0.w));
    pk.h2[2] = __float22bfloat162_rn(make_float2(x1.x, x1.y));
    pk.h2[3] = __float22bfloat162_rn(make_float2(x1.z, x1.w));
    return pk.u4;
}

__global__ __launch_bounds__(512, 4)
void spectral_mfma_kernel(const float* __restrict__ enc,
                          const float* __restrict__ W,
                          const float* __restrict__ bias,
                          float* __restrict__ out) {
    // shorts; A rows at [0,8192) (32 x 256), W rows at [8192,24576) (64 x 256)
    __shared__ unsigned short SH[24576];   // 48 KB

    const int t    = threadIdx.x;
    const int lane = t & 63;
    const int wv   = t >> 6;               // 0..7
    const int tile_r = blockIdx.x * TR;    // 32 | 128: no batch-segment straddle
    const int tile_c = blockIdx.y * TC;

    const float* __restrict__ srcA = enc + (size_t)(tile_r >> 7) * (size_t)(LSEQ * DDIM)
                                         + (size_t)(tile_r & 127) * KDIM;
    const float* __restrict__ srcW = W + (size_t)tile_c * KDIM;

    // ---- issue ALL global loads first (12 x float4 per thread), then
    //      convert + LDS-write: maximizes outstanding loads per wave ----
    float4 ra[2][2];   // A: 1024 slots (32 rows x 32), 2 per thread
    float4 rw[4][2];   // W: 2048 slots (64 rows x 32), 4 per thread
    #pragma unroll
    for (int i = 0; i < 2; ++i) {
        const int q = t + i * 512;
        const float* g = srcA + (size_t)(q >> 5) * KDIM + (q & 31) * 8;
        ra[i][0] = *(const float4*)g;
        ra[i][1] = *(const float4*)(g + 4);
    }
    #pragma unroll
    for (int i = 0; i < 4; ++i) {
        const int q = t + i * 512;
        const float* g = srcW + (size_t)(q >> 5) * KDIM + (q & 31) * 8;
        rw[i][0] = *(const float4*)g;
        rw[i][1] = *(const float4*)(g + 4);
    }
    #pragma unroll
    for (int i = 0; i < 2; ++i) {
        const int q = t + i * 512;
        const int r = q >> 5, s = q & 31;
        *(uint4*)&SH[(r * 32 + (s ^ (r & 15))) * 8] = pack8_bf16(ra[i][0], ra[i][1]);
    }
    #pragma unroll
    for (int i = 0; i < 4; ++i) {
        const int q = t + i * 512;
        const int r = q >> 5, s = q & 31;
        *(uint4*)&SH[8192 + (r * 32 + (s ^ (r & 15))) * 8] = pack8_bf16(rw[i][0], rw[i][1]);
    }
    __syncthreads();

    const int fm = lane & 15;              // frag row/col AND swizzle key
    const int kq = lane >> 4;              // k-quad
    const int m0 = (wv & 1) * 16;          // waves 2x4 over the 32x64 tile
    const int n0 = (wv >> 1) * 16;

    const int arow = (m0 + fm) * 256;
    const int wrow = 8192 + (n0 + fm) * 256;

    float4v acc = {0.f, 0.f, 0.f, 0.f};

    // ---- inner: 8 k-steps x (2 ds_read_b128 + 1 MFMA), one barrier total ----
    #pragma unroll
    for (int ks = 0; ks < 8; ++ks) {
        const int so = ((ks * 4 + kq) ^ fm) * 8;   // swizzled short offset
        const short8 a = *(const short8*)&SH[arow + so];
        const short8 b = *(const short8*)&SH[wrow + so];
        acc = __builtin_amdgcn_mfma_f32_16x16x32_bf16(a, b, acc, 0, 0, 0);
    }

    // ---- epilogue: scale + bias + tanh ----
    // C/D layout: col = lane&15, row = (lane>>4)*4 + reg   (m89)
    const int rbase = tile_r + m0 + kq * 4;
    const int c0 = tile_c + n0 + fm;
    const float bb = bias[c0];
    #pragma unroll
    for (int reg = 0; reg < 4; ++reg) {
        const int row = rbase + reg;
        const int n  = row & 3;            // sector
        const int li = (row >> 2) & 31;    // token index (< 32)
        const float scale = (n == 0 || (n == 1 && li >= 16)) ? 1.0f : COEF;
        out[(size_t)row * COLS + c0] = tanh_fast(scale * acc[reg] + bb);
    }
}

extern "C" void kernel_launch(void* const* d_in, const int* in_sizes, int n_in,
                              void* d_out, int out_size, void* d_ws, size_t ws_size,
                              hipStream_t stream) {
    const float* enc  = (const float*)d_in[0];   // [32, 512, 1024]
    const float* W    = (const float*)d_in[1];   // [256, 256]
    const float* bias = (const float*)d_in[2];   // [256]
    float* out = (float*)d_out;                  // [32, 32, 4, 256]

    dim3 grid(ROWS / TR, COLS / TC);             // 128 x 4 = 512 blocks
    spectral_mfma_kernel<<<grid, dim3(512), 0, stream>>>(enc, W, bias, out);
}